// Round 9
// baseline (269.267 us; speedup 1.0000x reference)
//
#include <hip/hip_runtime.h>

#define NB 8
#define NS 2048
#define ND 256
#define NH 4
#define NHD 64
#define ND2 512
#define NM (NB * NS)
#define PITCH 72            // padded LDS row pitch for Pl (bf16 elems)
#define C1 0.18033688f      // 0.125 * log2(e), prefolded into Q weights/bias

typedef __attribute__((ext_vector_type(8))) short          bf16x8;
typedef __attribute__((ext_vector_type(4))) float          f32x4;
typedef unsigned short ushort_t;
typedef unsigned int   uint_t;

#define MFMA16(a, b, c) __builtin_amdgcn_mfma_f32_16x16x32_bf16(a, b, c, 0, 0, 0)

#if __has_builtin(__builtin_amdgcn_exp2f)
#define EXP2(x) __builtin_amdgcn_exp2f(x)
#else
#define EXP2(x) exp2f(x)
#endif

static __device__ inline uint_t pack2bf(float a, float b) {
    union { float f; uint_t u; } x, y; x.f = a; y.f = b;
    return __builtin_amdgcn_perm(y.u + 0x8000u, x.u + 0x8000u, 0x07060302u);
}
static __device__ inline ushort_t f2bf(float f) {
    union { float f; uint_t u; } x; x.f = f;
    return (ushort_t)((x.u + 0x7FFFu + ((x.u >> 16) & 1u)) >> 16);
}

// ===========================================================================
// Fragment-major layout: matrix Mat[R][C] stored so the MFMA fragment
// (lane lq=l&15 holds Mat[r16*16+lq][kc*32+(l>>4)*8+j]) is one coalesced
// 16B/lane load: elem = ((r16*(C/32)+kc)*64 + lane)*8 + j.
// ===========================================================================

__global__ __launch_bounds__(256) void conv_frag(
    const float* __restrict__ d, const float* __restrict__ s,
    ushort_t* __restrict__ df, ushort_t* __restrict__ sf)
{
    const float* src = blockIdx.y ? s : d;
    ushort_t* dst    = blockIdx.y ? sf : df;
    const int g = blockIdx.x * 256 + threadIdx.x;
    const int lane = g & 63, ci = g >> 6;
    const int kc = ci & 7, r16 = ci >> 3;
    const int row = r16 * 16 + (lane & 15);
    const int c0  = kc * 32 + (lane >> 4) * 8;
    const float* p = src + (size_t)row * ND + c0;
    float4 a = *(const float4*)p;
    float4 b = *(const float4*)(p + 4);
    uint4 pk;
    pk.x = pack2bf(a.x, a.y); pk.y = pack2bf(a.z, a.w);
    pk.z = pack2bf(b.x, b.y); pk.w = pack2bf(b.z, b.w);
    *(uint4*)(dst + (size_t)g * 8) = pk;
}

__global__ __launch_bounds__(256) void wfrag(
    const float* q, const float* k, const float* v, const float* m1,
    ushort_t* qw, ushort_t* kw, ushort_t* vw, ushort_t* m1f)
{
    const float* src; ushort_t* dst; int K, N; float sc = 1.0f;
    switch (blockIdx.y) {
        case 0: src = q;  dst = qw;  K = 256; N = 256; sc = C1; break;
        case 1: src = k;  dst = kw;  K = 256; N = 256; break;
        case 2: src = v;  dst = vw;  K = 256; N = 256; break;
        default: src = m1; dst = m1f; K = 512; N = 256; break;
    }
    const int g = blockIdx.x * 256 + threadIdx.x;
    if (g >= (N * K) / 8) return;
    const int lane = g & 63, ci = g >> 6;
    const int lgck = (K == 512) ? 4 : 3;
    const int kc = ci & ((1 << lgck) - 1), n16 = ci >> lgck;
    const int n  = n16 * 16 + (lane & 15);
    const int k0 = kc * 32 + (lane >> 4) * 8;
    float f[8];
#pragma unroll
    for (int j = 0; j < 8; j++) f[j] = src[(size_t)(k0 + j) * N + n] * sc;
    uint4 pk;
    pk.x = pack2bf(f[0], f[1]); pk.y = pack2bf(f[2], f[3]);
    pk.z = pack2bf(f[4], f[5]); pk.w = pack2bf(f[6], f[7]);
    *(uint4*)(dst + (size_t)g * 8) = pk;
}

static __device__ inline void femit(ushort_t* buf, int n, int k, float v) {
    const int kc = k >> 5;
    const int lane = (((k >> 3) & 3) << 4) | (n & 15);
    const int j = k & 7;
    buf[((size_t)(((n >> 4) * 16 + kc) * 64 + lane)) * 8 + j] = f2bf(v);
}

// ---------------------------------------------------------------------------
// prep: fused MLP0 weight, coalesced. Block = o_w row i (staged to LDS once);
// lanes sweep n (coalesced m0_w reads). F[i][n] = sum_j o_w[i][j] m0b[j][n].
// ---------------------------------------------------------------------------
__global__ __launch_bounds__(256) void fuse_w(
    const float* __restrict__ o_w, const float* __restrict__ m0_w,
    const float* __restrict__ bng, const float* __restrict__ bnv,
    ushort_t* __restrict__ m0fF)
{
    __shared__ float ow[256];
    const int i = blockIdx.x;
    const int t = threadIdx.x;
    ow[t] = o_w[i * 256 + t];
    __syncthreads();
    float f0 = 0.f, f1 = 0.f;
#pragma unroll 4
    for (int j = 0; j < 256; j++) {
        const float w = ow[j];
        f0 += w * m0_w[(size_t)(256 + j) * 512 + t];
        f1 += w * m0_w[(size_t)(256 + j) * 512 + t + 256];
    }
    const float A0v = bng[t] * rsqrtf(bnv[t] + 1e-5f);
    const float A1v = bng[t + 256] * rsqrtf(bnv[t + 256] + 1e-5f);
    femit(m0fF, t, 256 + i, f0 * A0v);
    femit(m0fF, t + 256, 256 + i, f1 * A1v);
    femit(m0fF, t, i, m0_w[(size_t)i * 512 + t] * A0v);
    femit(m0fF, t + 256, i, m0_w[(size_t)i * 512 + t + 256] * A1v);
}

// prep: fused bias (coalesced over n). grid 2 x 256.
__global__ __launch_bounds__(256) void bias_f(
    const float* __restrict__ o_b, const float* __restrict__ m0_w,
    const float* __restrict__ m0_b,
    const float* __restrict__ bng, const float* __restrict__ bnb,
    const float* __restrict__ bnm, const float* __restrict__ bnv,
    float* __restrict__ biasf)
{
    const int n = blockIdx.x * 256 + threadIdx.x;
    float s = 0.f;
#pragma unroll 4
    for (int j = 0; j < 256; j++)
        s += o_b[j] * m0_w[(size_t)(256 + j) * 512 + n];
    const float A = bng[n] * rsqrtf(bnv[n] + 1e-5f);
    biasf[n] = (m0_b[n] + s - bnm[n]) * A + bnb[n];
}

__global__ __launch_bounds__(256) void make_mbias(
    const int* __restrict__ mask, float* __restrict__ mb)
{
    const int i = blockIdx.x * 256 + threadIdx.x;
    mb[i] = mask[i] ? 0.0f : -1e9f;
}

// ---------------------------------------------------------------------------
// GEMM core, register-blocked 4x4 with EXPLICIT double-buffered prefetch:
// frags for kc+1 issue before kc's MFMAs (independent registers -> one full
// iteration of load-latency cover). All-global frag-major, no LDS/barriers.
// ---------------------------------------------------------------------------
template <int KC, int AK, bool NAT>
static __device__ inline void core4(
    const ushort_t* __restrict__ A0, const ushort_t* __restrict__ A1,
    const ushort_t* __restrict__ WF, int t16, int n16, f32x4 acc[4][4])
{
    const int lane = threadIdx.x & 63;
    bf16x8 af[2][4], wf[2][4];
#pragma unroll
    for (int mt = 0; mt < 4; mt++)
        af[0][mt] = *(const bf16x8*)(A0 + ((size_t)((t16 + mt) * AK) * 64 + lane) * 8);
#pragma unroll
    for (int nt = 0; nt < 4; nt++)
        wf[0][nt] = *(const bf16x8*)(WF + ((size_t)((n16 + nt) * KC) * 64 + lane) * 8);
#pragma unroll
    for (int kc = 0; kc < KC; kc++) {
        const int cur = kc & 1, nxt = cur ^ 1;
        if (kc + 1 < KC) {
            const int kn = kc + 1;
            const ushort_t* Ab = (kn < AK) ? A0 : A1;
            const int kca = (kn < AK) ? kn : kn - AK;
#pragma unroll
            for (int mt = 0; mt < 4; mt++)
                af[nxt][mt] = *(const bf16x8*)(Ab + ((size_t)((t16 + mt) * AK + kca) * 64 + lane) * 8);
#pragma unroll
            for (int nt = 0; nt < 4; nt++)
                wf[nxt][nt] = *(const bf16x8*)(WF + ((size_t)((n16 + nt) * KC + kn) * 64 + lane) * 8);
        }
#pragma unroll
        for (int mt = 0; mt < 4; mt++)
#pragma unroll
            for (int nt = 0; nt < 4; nt++) {
                if (NAT) acc[mt][nt] = MFMA16(af[cur][mt], wf[cur][nt], acc[mt][nt]);
                else     acc[mt][nt] = MFMA16(wf[cur][nt], af[cur][mt], acc[mt][nt]);
            }
    }
}

// ---------------------------------------------------------------------------
// fused QKV. grid (4 heads, NM/256, 3); 4 waves t-split (wave 64 tok x 64 ch)
// ---------------------------------------------------------------------------
__global__ __launch_bounds__(256) void qkv_frag(
    const ushort_t* __restrict__ descF, const ushort_t* __restrict__ srcF,
    const ushort_t* __restrict__ qwF, const ushort_t* __restrict__ kwF,
    const ushort_t* __restrict__ vwF,
    const float* __restrict__ q_b, const float* __restrict__ k_b,
    const float* __restrict__ v_b,
    ushort_t* __restrict__ qF, ushort_t* __restrict__ kF,
    ushort_t* __restrict__ vF)
{
    const int t = threadIdx.x, w = t >> 6;
    const int lq = t & 15, lg = (t & 63) >> 4;
    const int h    = blockIdx.x;
    const int tok0 = (blockIdx.y << 8) + (w << 6);
    const int t16  = tok0 >> 4, n16 = h << 2;
    const int z    = blockIdx.z;

    f32x4 acc[4][4];
#pragma unroll
    for (int mt = 0; mt < 4; mt++)
#pragma unroll
        for (int nt = 0; nt < 4; nt++) acc[mt][nt] = (f32x4){0.f, 0.f, 0.f, 0.f};

    if (z == 2) {
        core4<8, 8, true>(srcF, srcF, vwF, t16, n16, acc);
#pragma unroll
        for (int nt = 0; nt < 4; nt++) {
            const int dvh = nt * 16 + lq;
            const float bs = v_b[h * 64 + dvh];
#pragma unroll
            for (int mt = 0; mt < 4; mt++) {
                const int tok = tok0 + mt * 16 + lg * 4;
                const int b = tok >> 11, s0 = tok & 2047;
                const int bh = b * NH + h;
                uint2 pv;
                pv.x = pack2bf(acc[mt][nt][0] + bs, acc[mt][nt][1] + bs);
                pv.y = pack2bf(acc[mt][nt][2] + bs, acc[mt][nt][3] + bs);
                const size_t e = (size_t)bh * 131072 +
                    ((size_t)((dvh >> 4) * 64 + (s0 >> 5)) * 64 +
                     (((s0 >> 3) & 3) * 16 + (dvh & 15))) * 8 + (s0 & 7);
                *(uint2*)(vF + e) = pv;
            }
        }
    } else {
        const ushort_t* A = z ? srcF : descF;
        const ushort_t* W = z ? kwF : qwF;
        const float* bias = z ? k_b : q_b;
        ushort_t* dst     = z ? kF : qF;
        const float bsc   = z ? 1.0f : C1;
        core4<8, 8, false>(A, A, W, t16, n16, acc);
#pragma unroll
        for (int nt = 0; nt < 4; nt++) {
            const int d0 = nt * 16 + lg * 4;
            f32x4 b4 = *(const f32x4*)(bias + h * 64 + d0);
#pragma unroll
            for (int mt = 0; mt < 4; mt++) {
                const int tok = tok0 + mt * 16 + lq;
                const int b = tok >> 11, s = tok & 2047;
                const int bh = b * NH + h;
                uint2 pv;
                pv.x = pack2bf(acc[mt][nt][0] + b4[0] * bsc,
                               acc[mt][nt][1] + b4[1] * bsc);
                pv.y = pack2bf(acc[mt][nt][2] + b4[2] * bsc,
                               acc[mt][nt][3] + b4[3] * bsc);
                const size_t e = (size_t)bh * 131072 +
                    ((size_t)((s >> 4) * 2 + (d0 >> 5)) * 64 +
                     (((d0 >> 3) & 3) * 16 + lq)) * 8 + (d0 & 7);
                *(uint2*)(dst + e) = pv;
            }
        }
    }
}

// ---------------------------------------------------------------------------
// MLP0 (out-proj+BN fused): h = relu([desc|ctx]@m0f + biasf). grid (8, NM/256)
// ---------------------------------------------------------------------------
__global__ __launch_bounds__(256) void mlp0_frag(
    const ushort_t* __restrict__ descF, const ushort_t* __restrict__ ctxF,
    const ushort_t* __restrict__ m0fF, const float* __restrict__ biasf,
    ushort_t* __restrict__ hF)
{
    const int t = threadIdx.x, w = t >> 6;
    const int lq = t & 15, lg = (t & 63) >> 4;
    const int n0   = blockIdx.x << 6;
    const int tok0 = (blockIdx.y << 8) + (w << 6);
    const int t16  = tok0 >> 4, n16 = n0 >> 4;

    f32x4 acc[4][4];
#pragma unroll
    for (int mt = 0; mt < 4; mt++)
#pragma unroll
        for (int nt = 0; nt < 4; nt++) acc[mt][nt] = (f32x4){0.f, 0.f, 0.f, 0.f};

    core4<16, 8, false>(descF, ctxF, m0fF, t16, n16, acc);

#pragma unroll
    for (int nt = 0; nt < 4; nt++) {
        const int c0 = n0 + nt * 16 + lg * 4;
        f32x4 b4 = *(const f32x4*)(biasf + c0);
#pragma unroll
        for (int mt = 0; mt < 4; mt++) {
            const int tok = tok0 + mt * 16 + lq;
            uint2 pv;
            pv.x = pack2bf(fmaxf(acc[mt][nt][0] + b4[0], 0.f),
                           fmaxf(acc[mt][nt][1] + b4[1], 0.f));
            pv.y = pack2bf(fmaxf(acc[mt][nt][2] + b4[2], 0.f),
                           fmaxf(acc[mt][nt][3] + b4[3], 0.f));
            const size_t e = ((size_t)((tok >> 4) * 16 + (c0 >> 5)) * 64 +
                              (((c0 >> 3) & 3) * 16 + lq)) * 8 + (c0 & 7);
            *(uint2*)(hF + e) = pv;
        }
    }
}

// ---------------------------------------------------------------------------
// MLP1: out = hF @ m1 + m1_b, fp32 row-major. grid (4, NM/256).
// ---------------------------------------------------------------------------
__global__ __launch_bounds__(256) void mlp1_frag(
    const ushort_t* __restrict__ hF, const ushort_t* __restrict__ m1F,
    const float* __restrict__ m1_b, float* __restrict__ out)
{
    const int t = threadIdx.x, w = t >> 6;
    const int lq = t & 15, lg = (t & 63) >> 4;
    const int n0   = blockIdx.x << 6;
    const int tok0 = (blockIdx.y << 8) + (w << 6);
    const int t16  = tok0 >> 4, n16 = n0 >> 4;

    f32x4 acc[4][4];
#pragma unroll
    for (int mt = 0; mt < 4; mt++)
#pragma unroll
        for (int nt = 0; nt < 4; nt++) acc[mt][nt] = (f32x4){0.f, 0.f, 0.f, 0.f};

    core4<16, 16, false>(hF, hF, m1F, t16, n16, acc);

#pragma unroll
    for (int nt = 0; nt < 4; nt++) {
        const int c0 = n0 + nt * 16 + lg * 4;
        f32x4 b4 = *(const f32x4*)(m1_b + c0);
#pragma unroll
        for (int mt = 0; mt < 4; mt++) {
            const int tok = tok0 + mt * 16 + lq;
            f32x4 o4;
#pragma unroll
            for (int j = 0; j < 4; j++) o4[j] = acc[mt][nt][j] + b4[j];
            *(f32x4*)(out + (size_t)tok * ND + c0) = o4;
        }
    }
}

// ---------------------------------------------------------------------------
// Flash cross-attention v4.1: identical pipeline to r8 (V frags at iteration
// top, K prefetch, deferred l-reduction) but 128-thread blocks, grid
// (NS/64, H, B) = 1024 blocks for finer scheduling granularity.
// ---------------------------------------------------------------------------
__global__ __launch_bounds__(128) void attn_frag(
    const ushort_t* __restrict__ qF, const ushort_t* __restrict__ kF,
    const ushort_t* __restrict__ vF, const float* __restrict__ mbias,
    ushort_t* __restrict__ ctxF)
{
    __shared__ ushort_t Pl[4][16 * PITCH];

    const int t = threadIdx.x, w = t >> 6, lane = t & 63;
    const int lq = t & 15, lg = lane >> 4;
    const int qb = blockIdx.x, h = blockIdx.y, b = blockIdx.z;
    const int bh = b * NH + h;

    const ushort_t* qh = qF + (size_t)bh * 131072;
    const ushort_t* kh = kF + (size_t)bh * 131072;
    const ushort_t* vh = vF + (size_t)bh * 131072;
    const float* mrow = mbias + b * NS;
    const int qrow0 = qb * 64 + w * 32;
    const int q16 = qrow0 >> 4;

    bf16x8 qf[2][2];
#pragma unroll
    for (int qt = 0; qt < 2; qt++)
#pragma unroll
        for (int kc = 0; kc < 2; kc++)
            qf[qt][kc] = *(const bf16x8*)(qh + ((size_t)((q16 + qt) * 2 + kc) * 64 + lane) * 8);

    f32x4 o[2][4];
#pragma unroll
    for (int qt = 0; qt < 2; qt++)
#pragma unroll
        for (int dt = 0; dt < 4; dt++) o[qt][dt] = (f32x4){0.f, 0.f, 0.f, 0.f};
    float l_part[2] = {0.0f, 0.0f};

    // preload K frags for chunk 0
    bf16x8 ka[4][2];
#pragma unroll
    for (int kt = 0; kt < 4; kt++)
#pragma unroll
        for (int kk = 0; kk < 2; kk++)
            ka[kt][kk] = *(const bf16x8*)(kh + ((size_t)((kt * 2 + kk) * 64 + lane)) * 8);

    for (int key0 = 0; key0 < NS; key0 += 64) {
        // V fragments for THIS chunk: issue now, consumed after softmax
        bf16x8 vf[4][2];
        const ushort_t* vb = vh + (size_t)(key0 >> 5) * 512;
#pragma unroll
        for (int dt = 0; dt < 4; dt++)
#pragma unroll
            for (int kh2 = 0; kh2 < 2; kh2++)
                vf[dt][kh2] = *(const bf16x8*)(vb +
                    ((size_t)((dt * 64 + kh2) * 64 + lane)) * 8);
        f32x4 mb[4];
#pragma unroll
        for (int kt = 0; kt < 4; kt++)
            mb[kt] = *(const f32x4*)(mrow + key0 + kt * 16 + lg * 4);

        // QK: S^T[key][q] for both q-tiles (C-layout: col = q = lq)
        f32x4 st[2][4];
#pragma unroll
        for (int qt = 0; qt < 2; qt++)
#pragma unroll
            for (int kt = 0; kt < 4; kt++) {
                f32x4 a = (f32x4){0.f, 0.f, 0.f, 0.f};
                a = MFMA16(ka[kt][0], qf[qt][0], a);
                a = MFMA16(ka[kt][1], qf[qt][1], a);
                st[qt][kt] = a;
            }

        // prefetch next chunk's K frags (wrap, branchless)
        const int keyn = (key0 + 64) & (NS - 1);
        const ushort_t* kb = kh + (size_t)keyn * 64;
        bf16x8 kn[4][2];
#pragma unroll
        for (int kt = 0; kt < 4; kt++)
#pragma unroll
            for (int kk = 0; kk < 2; kk++)
                kn[kt][kk] = *(const bf16x8*)(kb + ((size_t)((kt * 2 + kk) * 64 + lane)) * 8);

        // softmax numerator + P pack (no max-subtract: scores bounded)
#pragma unroll
        for (int qt = 0; qt < 2; qt++) {
            float ls = 0.0f;
#pragma unroll
            for (int kt = 0; kt < 4; kt++) {
                float pr[4];
#pragma unroll
                for (int r = 0; r < 4; r++) {
                    const float p = EXP2(st[qt][kt][r] + mb[kt][r]);
                    ls += p;
                    pr[r] = p;
                }
                uint2 pv;
                pv.x = pack2bf(pr[0], pr[1]);
                pv.y = pack2bf(pr[2], pr[3]);
                *(uint2*)&Pl[w * 2 + qt][lq * PITCH + kt * 16 + lg * 4] = pv;
            }
            l_part[qt] += ls;
        }

        bf16x8 pf[2][2];
#pragma unroll
        for (int qt = 0; qt < 2; qt++)
#pragma unroll
            for (int kh2 = 0; kh2 < 2; kh2++)
                pf[qt][kh2] = *(const bf16x8*)&Pl[w * 2 + qt][lq * PITCH + kh2 * 32 + lg * 8];

        // ctx^T += V^T·P
#pragma unroll
        for (int dt = 0; dt < 4; dt++)
#pragma unroll
            for (int kh2 = 0; kh2 < 2; kh2++)
#pragma unroll
                for (int qt = 0; qt < 2; qt++)
                    o[qt][dt] = MFMA16(vf[dt][kh2], pf[qt][kh2], o[qt][dt]);

        // rotate K double-buffer
#pragma unroll
        for (int kt = 0; kt < 4; kt++)
#pragma unroll
            for (int kk = 0; kk < 2; kk++)
                ka[kt][kk] = kn[kt][kk];
    }

    // final l reduction + epilogue (ctx frag-major bf16)
#pragma unroll
    for (int qt = 0; qt < 2; qt++) {
        float ls = l_part[qt];
        ls += __shfl_xor(ls, 16);
        ls += __shfl_xor(ls, 32);
        const float li = 1.0f / ls;
        const int tok16 = b * 128 + q16 + qt;
#pragma unroll
        for (int dt = 0; dt < 4; dt++) {
            const int c = h * 64 + dt * 16 + lg * 4;
            uint2 pv;
            pv.x = pack2bf(o[qt][dt][0] * li, o[qt][dt][1] * li);
            pv.y = pack2bf(o[qt][dt][2] * li, o[qt][dt][3] * li);
            const size_t e = ((size_t)(tok16 * 8 + (c >> 5)) * 64 +
                              (((c >> 3) & 3) * 16 + lq)) * 8 + (c & 7);
            *(uint2*)(ctxF + e) = pv;
        }
    }
}

extern "C" void kernel_launch(void* const* d_in, const int* in_sizes, int n_in,
                              void* d_out, int out_size, void* d_ws, size_t ws_size,
                              hipStream_t stream)
{
    (void)in_sizes; (void)n_in; (void)out_size; (void)ws_size;
    const float* desc = (const float*)d_in[0];
    const float* srcp = (const float*)d_in[1];
    const int*   mask = (const int*)d_in[2];
    const float* q_w  = (const float*)d_in[3];
    const float* q_b  = (const float*)d_in[4];
    const float* k_w  = (const float*)d_in[5];
    const float* k_b  = (const float*)d_in[6];
    const float* v_w  = (const float*)d_in[7];
    const float* v_b  = (const float*)d_in[8];
    const float* o_w  = (const float*)d_in[9];
    const float* o_b  = (const float*)d_in[10];
    const float* m0_w = (const float*)d_in[11];
    const float* m0_b = (const float*)d_in[12];
    const float* bng  = (const float*)d_in[13];
    const float* bnb  = (const float*)d_in[14];
    const float* bnm  = (const float*)d_in[15];
    const float* bnv  = (const float*)d_in[16];
    const float* m1_w = (const float*)d_in[17];
    const float* m1_b = (const float*)d_in[18];
    float* out = (float*)d_out;

    const size_t ASZ = (size_t)NM * ND;
    ushort_t* descF = (ushort_t*)d_ws;
    ushort_t* srcF  = descF + ASZ;
    ushort_t* qF    = descF + 2 * ASZ;
    ushort_t* kF    = descF + 3 * ASZ;
    ushort_t* vF    = descF + 4 * ASZ;
    ushort_t* qwF   = descF + 5 * ASZ;
    ushort_t* kwF   = qwF + 65536;
    ushort_t* vwF   = kwF + 65536;
    ushort_t* m1F   = vwF + 65536;
    ushort_t* m0fF  = m1F + 131072;
    float*    biasf = (float*)(m0fF + 262144);
    float*    mbias = biasf + 512;
    ushort_t* ctxF  = srcF;   // src dead after QKV
    ushort_t* hF    = qF;     // q+k dead after attention

    const dim3 blk(256);

    conv_frag<<<dim3(2048, 2), blk, 0, stream>>>(desc, srcp, descF, srcF);
    wfrag<<<dim3(64, 4), blk, 0, stream>>>(q_w, k_w, v_w, m1_w, qwF, kwF, vwF, m1F);
    fuse_w<<<dim3(256), blk, 0, stream>>>(o_w, m0_w, bng, bnv, m0fF);
    bias_f<<<dim3(2), blk, 0, stream>>>(o_b, m0_w, m0_b, bng, bnb, bnm, bnv, biasf);
    make_mbias<<<dim3(64), blk, 0, stream>>>(mask, mbias);

    qkv_frag<<<dim3(4, NM / 256, 3), blk, 0, stream>>>(
        descF, srcF, qwF, kwF, vwF, q_b, k_b, v_b, qF, kF, vF);
    attn_frag<<<dim3(NS / 64, NH, NB), dim3(128), 0, stream>>>(qF, kF, vF, mbias, ctxF);
    mlp0_frag<<<dim3(8, NM / 256), blk, 0, stream>>>(descF, ctxF, m0fF, biasf, hF);
    mlp1_frag<<<dim3(4, NM / 256), blk, 0, stream>>>(hF, m1F, m1_b, out);
}

// Round 10
// 239.778 us; speedup vs baseline: 1.1230x; 1.1230x over previous
//
#include <hip/hip_runtime.h>

#define NB 8
#define NS 2048
#define ND 256
#define NH 4
#define NHD 64
#define ND2 512
#define NM (NB * NS)
#define PITCH 72            // padded LDS row pitch for Pl (bf16 elems)
#define C1 0.18033688f      // 0.125 * log2(e), prefolded into Q weights/bias

typedef __attribute__((ext_vector_type(8))) short          bf16x8;
typedef __attribute__((ext_vector_type(4))) float          f32x4;
typedef unsigned short ushort_t;
typedef unsigned int   uint_t;

#define MFMA16(a, b, c) __builtin_amdgcn_mfma_f32_16x16x32_bf16(a, b, c, 0, 0, 0)

#if __has_builtin(__builtin_amdgcn_exp2f)
#define EXP2(x) __builtin_amdgcn_exp2f(x)
#else
#define EXP2(x) exp2f(x)
#endif

static __device__ inline uint_t pack2bf(float a, float b) {
    union { float f; uint_t u; } x, y; x.f = a; y.f = b;
    return __builtin_amdgcn_perm(y.u + 0x8000u, x.u + 0x8000u, 0x07060302u);
}
static __device__ inline ushort_t f2bf(float f) {
    union { float f; uint_t u; } x; x.f = f;
    return (ushort_t)((x.u + 0x7FFFu + ((x.u >> 16) & 1u)) >> 16);
}

// ===========================================================================
// Fragment-major layout: matrix Mat[R][C] stored so the MFMA fragment
// (lane lq=l&15 holds Mat[r16*16+lq][kc*32+(l>>4)*8+j]) is one coalesced
// 16B/lane load: elem = ((r16*(C/32)+kc)*64 + lane)*8 + j.
// ===========================================================================

static __device__ inline void femit(ushort_t* buf, int n, int k, float v) {
    const int kc = k >> 5;
    const int lane = (((k >> 3) & 3) << 4) | (n & 15);
    const int j = k & 7;
    buf[((size_t)(((n >> 4) * 16 + kc) * 64 + lane)) * 8 + j] = f2bf(v);
}

// ---------------------------------------------------------------------------
// ONE fused prep dispatch (all parts independent; switch on block range):
//  [0,4096)    conv: desc/src fp32 -> frag-major bf16
//  [4096,4352) wfrag: q/k/v/m1 weights -> frag-major bf16 W^T (Q scaled C1)
//  [4352,4416) mask -> additive bias
//  [4416,4672) fuse_w: F = o_w@m0b folded with BN -> m0fF (coalesced)
//  [4672,4688) bias_f: fused MLP0 bias (8 lanes per n + shfl reduce)
// ---------------------------------------------------------------------------
__global__ __launch_bounds__(256) void prep(
    const float* __restrict__ desc, const float* __restrict__ srcp,
    const int* __restrict__ mask,
    const float* __restrict__ q_w, const float* __restrict__ k_w,
    const float* __restrict__ v_w, const float* __restrict__ m1_w,
    const float* __restrict__ o_w, const float* __restrict__ o_b,
    const float* __restrict__ m0_w, const float* __restrict__ m0_b,
    const float* __restrict__ bng, const float* __restrict__ bnb,
    const float* __restrict__ bnm, const float* __restrict__ bnv,
    ushort_t* __restrict__ descF, ushort_t* __restrict__ srcF,
    ushort_t* __restrict__ qwF, ushort_t* __restrict__ kwF,
    ushort_t* __restrict__ vwF, ushort_t* __restrict__ m1F,
    ushort_t* __restrict__ m0fF, float* __restrict__ biasf,
    float* __restrict__ mbias)
{
    __shared__ float ow[256];
    const int blk = blockIdx.x;
    const int t = threadIdx.x;

    if (blk < 4096) {
        // ---- activations fp32 -> frag-major bf16 ----
        const int y = blk >> 11, x = blk & 2047;
        const float* src = y ? srcp : desc;
        ushort_t* dst    = y ? srcF : descF;
        const int g = x * 256 + t;
        const int lane = g & 63, ci = g >> 6;
        const int kc = ci & 7, r16 = ci >> 3;
        const int row = r16 * 16 + (lane & 15);
        const int c0  = kc * 32 + (lane >> 4) * 8;
        const float* p = src + (size_t)row * ND + c0;
        float4 a = *(const float4*)p;
        float4 b = *(const float4*)(p + 4);
        uint4 pk;
        pk.x = pack2bf(a.x, a.y); pk.y = pack2bf(a.z, a.w);
        pk.z = pack2bf(b.x, b.y); pk.w = pack2bf(b.z, b.w);
        *(uint4*)(dst + (size_t)g * 8) = pk;
    } else if (blk < 4352) {
        // ---- weight transpose/convert ----
        const int wb = blk - 4096;
        const int y = wb >> 6, x = wb & 63;
        const float* src; ushort_t* dst; int K, N; float sc = 1.0f;
        switch (y) {
            case 0: src = q_w; dst = qwF; K = 256; N = 256; sc = C1; break;
            case 1: src = k_w; dst = kwF; K = 256; N = 256; break;
            case 2: src = v_w; dst = vwF; K = 256; N = 256; break;
            default: src = m1_w; dst = m1F; K = 512; N = 256; break;
        }
        const int g = x * 256 + t;
        if (g >= (N * K) / 8) return;
        const int lane = g & 63, ci = g >> 6;
        const int lgck = (K == 512) ? 4 : 3;
        const int kc = ci & ((1 << lgck) - 1), n16 = ci >> lgck;
        const int n  = n16 * 16 + (lane & 15);
        const int k0 = kc * 32 + (lane >> 4) * 8;
        float f[8];
#pragma unroll
        for (int j = 0; j < 8; j++) f[j] = src[(size_t)(k0 + j) * N + n] * sc;
        uint4 pk;
        pk.x = pack2bf(f[0], f[1]); pk.y = pack2bf(f[2], f[3]);
        pk.z = pack2bf(f[4], f[5]); pk.w = pack2bf(f[6], f[7]);
        *(uint4*)(dst + (size_t)g * 8) = pk;
    } else if (blk < 4416) {
        // ---- mask -> additive bias ----
        const int i = (blk - 4352) * 256 + t;
        mbias[i] = mask[i] ? 0.0f : -1e9f;
    } else if (blk < 4672) {
        // ---- fused MLP0 weight (coalesced; block = o_w row i) ----
        const int i = blk - 4416;
        ow[t] = o_w[i * 256 + t];
        __syncthreads();
        float f0 = 0.f, f1 = 0.f;
#pragma unroll 4
        for (int j = 0; j < 256; j++) {
            const float w = ow[j];
            f0 += w * m0_w[(size_t)(256 + j) * 512 + t];
            f1 += w * m0_w[(size_t)(256 + j) * 512 + t + 256];
        }
        const float A0v = bng[t] * rsqrtf(bnv[t] + 1e-5f);
        const float A1v = bng[t + 256] * rsqrtf(bnv[t + 256] + 1e-5f);
        femit(m0fF, t, 256 + i, f0 * A0v);
        femit(m0fF, t + 256, 256 + i, f1 * A1v);
        femit(m0fF, t, i, m0_w[(size_t)i * 512 + t] * A0v);
        femit(m0fF, t + 256, i, m0_w[(size_t)i * 512 + t + 256] * A1v);
    } else {
        // ---- fused MLP0 bias: 8 lanes per n, shfl-reduce ----
        const int bb = blk - 4672;          // [0,16)
        const int n  = bb * 32 + (t >> 3);
        const int jp = t & 7;
        float s = 0.f;
#pragma unroll 4
        for (int j = jp * 32; j < jp * 32 + 32; j++)
            s += o_b[j] * m0_w[(size_t)(256 + j) * 512 + n];
        s += __shfl_xor(s, 1);
        s += __shfl_xor(s, 2);
        s += __shfl_xor(s, 4);
        if (jp == 0) {
            const float A = bng[n] * rsqrtf(bnv[n] + 1e-5f);
            biasf[n] = (m0_b[n] + s - bnm[n]) * A + bnb[n];
        }
    }
}

// ---------------------------------------------------------------------------
// GEMM core (r8-proven, NO explicit prefetch — r9's double-buffer spilled):
// wave-tile MT*16 tok x 64 ch. All-global frag-major, no LDS, no barriers.
// ---------------------------------------------------------------------------
template <int KC, int AK, bool NAT, int MT>
static __device__ inline void core(
    const ushort_t* __restrict__ A0, const ushort_t* __restrict__ A1,
    const ushort_t* __restrict__ WF, int t16, int n16, f32x4 acc[MT][4])
{
    const int lane = threadIdx.x & 63;
#pragma unroll
    for (int kc = 0; kc < KC; kc++) {
        const ushort_t* Ab = (kc < AK) ? A0 : A1;
        const int kca = (kc < AK) ? kc : kc - AK;
        bf16x8 af[MT], wf[4];
#pragma unroll
        for (int mt = 0; mt < MT; mt++)
            af[mt] = *(const bf16x8*)(Ab + ((size_t)((t16 + mt) * AK + kca) * 64 + lane) * 8);
#pragma unroll
        for (int nt = 0; nt < 4; nt++)
            wf[nt] = *(const bf16x8*)(WF + ((size_t)((n16 + nt) * KC + kc) * 64 + lane) * 8);
#pragma unroll
        for (int mt = 0; mt < MT; mt++)
#pragma unroll
            for (int nt = 0; nt < 4; nt++) {
                if (NAT) acc[mt][nt] = MFMA16(af[mt], wf[nt], acc[mt][nt]);
                else     acc[mt][nt] = MFMA16(wf[nt], af[mt], acc[mt][nt]);
            }
    }
}

// ---------------------------------------------------------------------------
// fused QKV. grid (4 heads, NM/256, 3); 4 waves t-split (wave 64 tok x 64 ch)
// ---------------------------------------------------------------------------
__global__ __launch_bounds__(256) void qkv_frag(
    const ushort_t* __restrict__ descF, const ushort_t* __restrict__ srcF,
    const ushort_t* __restrict__ qwF, const ushort_t* __restrict__ kwF,
    const ushort_t* __restrict__ vwF,
    const float* __restrict__ q_b, const float* __restrict__ k_b,
    const float* __restrict__ v_b,
    ushort_t* __restrict__ qF, ushort_t* __restrict__ kF,
    ushort_t* __restrict__ vF)
{
    const int t = threadIdx.x, w = t >> 6;
    const int lq = t & 15, lg = (t & 63) >> 4;
    const int h    = blockIdx.x;
    const int tok0 = (blockIdx.y << 8) + (w << 6);
    const int t16  = tok0 >> 4, n16 = h << 2;
    const int z    = blockIdx.z;

    f32x4 acc[4][4];
#pragma unroll
    for (int mt = 0; mt < 4; mt++)
#pragma unroll
        for (int nt = 0; nt < 4; nt++) acc[mt][nt] = (f32x4){0.f, 0.f, 0.f, 0.f};

    if (z == 2) {
        core<8, 8, true, 4>(srcF, srcF, vwF, t16, n16, acc);
#pragma unroll
        for (int nt = 0; nt < 4; nt++) {
            const int dvh = nt * 16 + lq;
            const float bs = v_b[h * 64 + dvh];
#pragma unroll
            for (int mt = 0; mt < 4; mt++) {
                const int tok = tok0 + mt * 16 + lg * 4;
                const int b = tok >> 11, s0 = tok & 2047;
                const int bh = b * NH + h;
                uint2 pv;
                pv.x = pack2bf(acc[mt][nt][0] + bs, acc[mt][nt][1] + bs);
                pv.y = pack2bf(acc[mt][nt][2] + bs, acc[mt][nt][3] + bs);
                const size_t e = (size_t)bh * 131072 +
                    ((size_t)((dvh >> 4) * 64 + (s0 >> 5)) * 64 +
                     (((s0 >> 3) & 3) * 16 + (dvh & 15))) * 8 + (s0 & 7);
                *(uint2*)(vF + e) = pv;
            }
        }
    } else {
        const ushort_t* A = z ? srcF : descF;
        const ushort_t* W = z ? kwF : qwF;
        const float* bias = z ? k_b : q_b;
        ushort_t* dst     = z ? kF : qF;
        const float bsc   = z ? 1.0f : C1;
        core<8, 8, false, 4>(A, A, W, t16, n16, acc);
#pragma unroll
        for (int nt = 0; nt < 4; nt++) {
            const int d0 = nt * 16 + lg * 4;
            f32x4 b4 = *(const f32x4*)(bias + h * 64 + d0);
#pragma unroll
            for (int mt = 0; mt < 4; mt++) {
                const int tok = tok0 + mt * 16 + lq;
                const int b = tok >> 11, s = tok & 2047;
                const int bh = b * NH + h;
                uint2 pv;
                pv.x = pack2bf(acc[mt][nt][0] + b4[0] * bsc,
                               acc[mt][nt][1] + b4[1] * bsc);
                pv.y = pack2bf(acc[mt][nt][2] + b4[2] * bsc,
                               acc[mt][nt][3] + b4[3] * bsc);
                const size_t e = (size_t)bh * 131072 +
                    ((size_t)((s >> 4) * 2 + (d0 >> 5)) * 64 +
                     (((d0 >> 3) & 3) * 16 + lq)) * 8 + (d0 & 7);
                *(uint2*)(dst + e) = pv;
            }
        }
    }
}

// ---------------------------------------------------------------------------
// MLP0 (out-proj+BN fused): h = relu([desc|ctx]@m0f + biasf). grid (8, NM/256)
// ---------------------------------------------------------------------------
__global__ __launch_bounds__(256) void mlp0_frag(
    const ushort_t* __restrict__ descF, const ushort_t* __restrict__ ctxF,
    const ushort_t* __restrict__ m0fF, const float* __restrict__ biasf,
    ushort_t* __restrict__ hF)
{
    const int t = threadIdx.x, w = t >> 6;
    const int lq = t & 15, lg = (t & 63) >> 4;
    const int n0   = blockIdx.x << 6;
    const int tok0 = (blockIdx.y << 8) + (w << 6);
    const int t16  = tok0 >> 4, n16 = n0 >> 4;

    f32x4 acc[4][4];
#pragma unroll
    for (int mt = 0; mt < 4; mt++)
#pragma unroll
        for (int nt = 0; nt < 4; nt++) acc[mt][nt] = (f32x4){0.f, 0.f, 0.f, 0.f};

    core<16, 8, false, 4>(descF, ctxF, m0fF, t16, n16, acc);

#pragma unroll
    for (int nt = 0; nt < 4; nt++) {
        const int c0 = n0 + nt * 16 + lg * 4;
        f32x4 b4 = *(const f32x4*)(biasf + c0);
#pragma unroll
        for (int mt = 0; mt < 4; mt++) {
            const int tok = tok0 + mt * 16 + lq;
            uint2 pv;
            pv.x = pack2bf(fmaxf(acc[mt][nt][0] + b4[0], 0.f),
                           fmaxf(acc[mt][nt][1] + b4[1], 0.f));
            pv.y = pack2bf(fmaxf(acc[mt][nt][2] + b4[2], 0.f),
                           fmaxf(acc[mt][nt][3] + b4[3], 0.f));
            const size_t e = ((size_t)((tok >> 4) * 16 + (c0 >> 5)) * 64 +
                              (((c0 >> 3) & 3) * 16 + lq)) * 8 + (c0 & 7);
            *(uint2*)(hF + e) = pv;
        }
    }
}

// ---------------------------------------------------------------------------
// MLP1: out = hF @ m1 + m1_b, fp32 row-major. MT=2 (wave 32 tok x 64 ch),
// grid (4, NM/128) = 512 blocks (2/CU; the old 256-block grid was 1/CU).
// ---------------------------------------------------------------------------
__global__ __launch_bounds__(256) void mlp1_frag(
    const ushort_t* __restrict__ hF, const ushort_t* __restrict__ m1F,
    const float* __restrict__ m1_b, float* __restrict__ out)
{
    const int t = threadIdx.x, w = t >> 6;
    const int lq = t & 15, lg = (t & 63) >> 4;
    const int n0   = blockIdx.x << 6;
    const int tok0 = (blockIdx.y << 7) + (w << 5);
    const int t16  = tok0 >> 4, n16 = n0 >> 4;

    f32x4 acc[2][4];
#pragma unroll
    for (int mt = 0; mt < 2; mt++)
#pragma unroll
        for (int nt = 0; nt < 4; nt++) acc[mt][nt] = (f32x4){0.f, 0.f, 0.f, 0.f};

    core<16, 16, false, 2>(hF, hF, m1F, t16, n16, acc);

#pragma unroll
    for (int nt = 0; nt < 4; nt++) {
        const int c0 = n0 + nt * 16 + lg * 4;
        f32x4 b4 = *(const f32x4*)(m1_b + c0);
#pragma unroll
        for (int mt = 0; mt < 2; mt++) {
            const int tok = tok0 + mt * 16 + lq;
            f32x4 o4;
#pragma unroll
            for (int j = 0; j < 4; j++) o4[j] = acc[mt][nt][j] + b4[j];
            *(f32x4*)(out + (size_t)tok * ND + c0) = o4;
        }
    }
}

// ---------------------------------------------------------------------------
// Flash cross-attention (r8-proven pipeline: V frags at iteration top,
// K prefetch, deferred l-reduction; 256 thr, grid (NS/128, H, B))
// + XCD-locality swizzle: all 16 q-blocks of one (b,h) share flat%8 so they
// land on one XCD; 4 bh-groups/XCD = 2 MB K/V fits the 4 MB per-XCD L2.
// ---------------------------------------------------------------------------
__global__ __launch_bounds__(256) void attn_frag(
    const ushort_t* __restrict__ qF, const ushort_t* __restrict__ kF,
    const ushort_t* __restrict__ vF, const float* __restrict__ mbias,
    ushort_t* __restrict__ ctxF)
{
    __shared__ ushort_t Pl[8][16 * PITCH];

    const int t = threadIdx.x, w = t >> 6, lane = t & 63;
    const int lq = t & 15, lg = lane >> 4;
    // swizzle: flat = x + 16y + 64z in [0,512)
    const int flat = blockIdx.x + (blockIdx.y << 4) + (blockIdx.z << 6);
    const int bh = (flat & 7) + (((flat >> 7) & 3) << 3);  // [0,32)
    const int qb = (flat >> 3) & 15;
    const int b = bh >> 2, h = bh & 3;
    (void)b; (void)h;

    const ushort_t* qh = qF + (size_t)bh * 131072;
    const ushort_t* kh = kF + (size_t)bh * 131072;
    const ushort_t* vh = vF + (size_t)bh * 131072;
    const float* mrow = mbias + (bh >> 2) * NS;
    const int qrow0 = qb * 128 + w * 32;
    const int q16 = qrow0 >> 4;

    bf16x8 qf[2][2];
#pragma unroll
    for (int qt = 0; qt < 2; qt++)
#pragma unroll
        for (int kc = 0; kc < 2; kc++)
            qf[qt][kc] = *(const bf16x8*)(qh + ((size_t)((q16 + qt) * 2 + kc) * 64 + lane) * 8);

    f32x4 o[2][4];
#pragma unroll
    for (int qt = 0; qt < 2; qt++)
#pragma unroll
        for (int dt = 0; dt < 4; dt++) o[qt][dt] = (f32x4){0.f, 0.f, 0.f, 0.f};
    float l_part[2] = {0.0f, 0.0f};

    // preload K frags for chunk 0
    bf16x8 ka[4][2];
#pragma unroll
    for (int kt = 0; kt < 4; kt++)
#pragma unroll
        for (int kk = 0; kk < 2; kk++)
            ka[kt][kk] = *(const bf16x8*)(kh + ((size_t)((kt * 2 + kk) * 64 + lane)) * 8);

    for (int key0 = 0; key0 < NS; key0 += 64) {
        // V fragments for THIS chunk: issue now, consumed after softmax
        bf16x8 vf[4][2];
        const ushort_t* vb = vh + (size_t)(key0 >> 5) * 512;
#pragma unroll
        for (int dt = 0; dt < 4; dt++)
#pragma unroll
            for (int kh2 = 0; kh2 < 2; kh2++)
                vf[dt][kh2] = *(const bf16x8*)(vb +
                    ((size_t)((dt * 64 + kh2) * 64 + lane)) * 8);
        f32x4 mb[4];
#pragma unroll
        for (int kt = 0; kt < 4; kt++)
            mb[kt] = *(const f32x4*)(mrow + key0 + kt * 16 + lg * 4);

        // QK: S^T[key][q] for both q-tiles (C-layout: col = q = lq)
        f32x4 st[2][4];
#pragma unroll
        for (int qt = 0; qt < 2; qt++)
#pragma unroll
            for (int kt = 0; kt < 4; kt++) {
                f32x4 a = (f32x4){0.f, 0.f, 0.f, 0.f};
                a = MFMA16(ka[kt][0], qf[qt][0], a);
                a = MFMA16(ka[kt][1], qf[qt][1], a);
                st[qt][kt] = a;
            }

        // prefetch next chunk's K frags (wrap, branchless)
        const int keyn = (key0 + 64) & (NS - 1);
        const ushort_t* kb = kh + (size_t)keyn * 64;
        bf16x8 kn[4][2];
#pragma unroll
        for (int kt = 0; kt < 4; kt++)
#pragma unroll
            for (int kk = 0; kk < 2; kk++)
                kn[kt][kk] = *(const bf16x8*)(kb + ((size_t)((kt * 2 + kk) * 64 + lane)) * 8);

        // softmax numerator + P pack (no max-subtract: scores bounded)
#pragma unroll
        for (int qt = 0; qt < 2; qt++) {
            float ls = 0.0f;
#pragma unroll
            for (int kt = 0; kt < 4; kt++) {
                float pr[4];
#pragma unroll
                for (int r = 0; r < 4; r++) {
                    const float p = EXP2(st[qt][kt][r] + mb[kt][r]);
                    ls += p;
                    pr[r] = p;
                }
                uint2 pv;
                pv.x = pack2bf(pr[0], pr[1]);
                pv.y = pack2bf(pr[2], pr[3]);
                *(uint2*)&Pl[w * 2 + qt][lq * PITCH + kt * 16 + lg * 4] = pv;
            }
            l_part[qt] += ls;
        }

        bf16x8 pf[2][2];
#pragma unroll
        for (int qt = 0; qt < 2; qt++)
#pragma unroll
            for (int kh2 = 0; kh2 < 2; kh2++)
                pf[qt][kh2] = *(const bf16x8*)&Pl[w * 2 + qt][lq * PITCH + kh2 * 32 + lg * 8];

        // ctx^T += V^T·P
#pragma unroll
        for (int dt = 0; dt < 4; dt++)
#pragma unroll
            for (int kh2 = 0; kh2 < 2; kh2++)
#pragma unroll
                for (int qt = 0; qt < 2; qt++)
                    o[qt][dt] = MFMA16(vf[dt][kh2], pf[qt][kh2], o[qt][dt]);

        // rotate K double-buffer
#pragma unroll
        for (int kt = 0; kt < 4; kt++)
#pragma unroll
            for (int kk = 0; kk < 2; kk++)
                ka[kt][kk] = kn[kt][kk];
    }

    // final l reduction + epilogue (ctx frag-major bf16)
#pragma unroll
    for (int qt = 0; qt < 2; qt++) {
        float ls = l_part[qt];
        ls += __shfl_xor(ls, 16);
        ls += __shfl_xor(ls, 32);
        const float li = 1.0f / ls;
        const int tok16 = (bh >> 2) * 128 + q16 + qt;
#pragma unroll
        for (int dt = 0; dt < 4; dt++) {
            const int c = (bh & 3) * 64 + dt * 16 + lg * 4;
            uint2 pv;
            pv.x = pack2bf(o[qt][dt][0] * li, o[qt][dt][1] * li);
            pv.y = pack2bf(o[qt][dt][2] * li, o[qt][dt][3] * li);
            const size_t e = ((size_t)(tok16 * 8 + (c >> 5)) * 64 +
                              (((c >> 3) & 3) * 16 + lq)) * 8 + (c & 7);
            *(uint2*)(ctxF + e) = pv;
        }
    }
}

extern "C" void kernel_launch(void* const* d_in, const int* in_sizes, int n_in,
                              void* d_out, int out_size, void* d_ws, size_t ws_size,
                              hipStream_t stream)
{
    (void)in_sizes; (void)n_in; (void)out_size; (void)ws_size;
    const float* desc = (const float*)d_in[0];
    const float* srcp = (const float*)d_in[1];
    const int*   mask = (const int*)d_in[2];
    const float* q_w  = (const float*)d_in[3];
    const float* q_b  = (const float*)d_in[4];
    const float* k_w  = (const float*)d_in[5];
    const float* k_b  = (const float*)d_in[6];
    const float* v_w  = (const float*)d_in[7];
    const float* v_b  = (const float*)d_in[8];
    const float* o_w  = (const float*)d_in[9];
    const float* o_b  = (const float*)d_in[10];
    const float* m0_w = (const float*)d_in[11];
    const float* m0_b = (const float*)d_in[12];
    const float* bng  = (const float*)d_in[13];
    const float* bnb  = (const float*)d_in[14];
    const float* bnm  = (const float*)d_in[15];
    const float* bnv  = (const float*)d_in[16];
    const float* m1_w = (const float*)d_in[17];
    const float* m1_b = (const float*)d_in[18];
    float* out = (float*)d_out;

    const size_t ASZ = (size_t)NM * ND;
    ushort_t* descF = (ushort_t*)d_ws;
    ushort_t* srcF  = descF + ASZ;
    ushort_t* qF    = descF + 2 * ASZ;
    ushort_t* kF    = descF + 3 * ASZ;
    ushort_t* vF    = descF + 4 * ASZ;
    ushort_t* qwF   = descF + 5 * ASZ;
    ushort_t* kwF   = qwF + 65536;
    ushort_t* vwF   = kwF + 65536;
    ushort_t* m1F   = vwF + 65536;
    ushort_t* m0fF  = m1F + 131072;
    float*    biasf = (float*)(m0fF + 262144);
    float*    mbias = biasf + 512;
    ushort_t* ctxF  = srcF;   // src dead after QKV
    ushort_t* hF    = qF;     // q+k dead after attention

    const dim3 blk(256);

    prep<<<dim3(4688), blk, 0, stream>>>(
        desc, srcp, mask, q_w, k_w, v_w, m1_w, o_w, o_b, m0_w, m0_b,
        bng, bnb, bnm, bnv, descF, srcF, qwF, kwF, vwF, m1F, m0fF, biasf, mbias);

    qkv_frag<<<dim3(4, NM / 256, 3), blk, 0, stream>>>(
        descF, srcF, qwF, kwF, vwF, q_b, k_b, v_b, qF, kF, vF);
    attn_frag<<<dim3(NS / 128, NH, NB), blk, 0, stream>>>(qF, kF, vF, mbias, ctxF);
    mlp0_frag<<<dim3(8, NM / 256), blk, 0, stream>>>(descF, ctxF, m0fF, biasf, hF);
    mlp1_frag<<<dim3(4, NM / 128), blk, 0, stream>>>(hF, m1F, m1_b, out);
}